// Round 7
// baseline (195.717 us; speedup 1.0000x reference)
//
#include <hip/hip_runtime.h>

// Problem: B=128, V=1024, T=1024, C=1024
#define B_ 128
#define V_ 1024
#define T_ 1024
#define C_ 1024
#define KK 2048  // T_ + V_
#define NZ 32    // k-slabs in fused k3 phase (K=64 each)
#define NBLK 256

// Degree-9 Taylor coefficients of f(s) = exp(tanh(s)).
constexpr float C9v[10] = {1.0f,          1.0f,          0.5f,
                           -0.166666667f, -0.291666667f, -0.025f,
                           0.134722222f,  0.054563493f,  -0.051165675f,
                           -0.041377307f};
// Binomial coefficients C(j,p), j<=9
constexpr float BN[10][10] = {
    {1, 0, 0, 0, 0, 0, 0, 0, 0, 0},
    {1, 1, 0, 0, 0, 0, 0, 0, 0, 0},
    {1, 2, 1, 0, 0, 0, 0, 0, 0, 0},
    {1, 3, 3, 1, 0, 0, 0, 0, 0, 0},
    {1, 4, 6, 4, 1, 0, 0, 0, 0, 0},
    {1, 5, 10, 10, 5, 1, 0, 0, 0, 0},
    {1, 6, 15, 20, 15, 6, 1, 0, 0, 0},
    {1, 7, 21, 35, 35, 21, 7, 1, 0, 0},
    {1, 8, 28, 56, 70, 56, 28, 8, 1, 0},
    {1, 9, 36, 84, 126, 126, 84, 36, 9, 1}};
constexpr float FACT[10] = {1.f, 1.f, 2.f, 6.f, 24.f, 120.f,
                            720.f, 5040.f, 40320.f, 362880.f};
constexpr float IFC[10] = {1.f, 1.f, 0.5f, 1.f / 6.f, 1.f / 24.f,
                           1.f / 120.f, 1.f / 720.f, 1.f / 5040.f,
                           1.f / 40320.f, 1.f / 362880.f};

// R6 post-mortem: flat 256-arrival barrier still ~50 us each. Both remaining
// mechanisms (same-line RMW serialization on arrival; 255 pollers on one gen
// line) stem from concentrating 256 agents on one cacheline. Fix (G12):
// two-level tree. Arrival: 8 group ctrs (32 RMWs each, parallel lines) ->
// 8-entry root. Broadcast: leaders poll root_gen, bump group gen -> <=32
// pollers/line. Resets ordered before release-bump (proven R5/R6 scheme).
__device__ int grp_ctr[8 * 32];  // 128 B apart
__device__ int grp_gen[8 * 32];
__device__ int root_ctr = 0;
__device__ int root_gen = 0;
__device__ int g_gctr[8 * 32];  // k3->k4 per-c-group counters
__device__ int g_ggen[8 * 32];

__device__ __forceinline__ void spin_gen(int* gen, int mygen) {
  int spins = 0;
  while (__hip_atomic_load(gen, __ATOMIC_RELAXED, __HIP_MEMORY_SCOPE_AGENT) ==
         mygen) {
    __builtin_amdgcn_s_sleep(4);
    if (++spins > (1 << 20)) break;  // failsafe: no infinite hang
  }
}

// Grid-wide tree barrier (256 blocks, groups of 32 by bid>>5).
__device__ __forceinline__ void tree_barrier(int bid) {
  __threadfence();   // release: drain this block's global writes (once)
  __syncthreads();
  if (threadIdx.x == 0) {
    const int g = bid >> 5;
    int* gctr = &grp_ctr[g * 32];
    int* ggen = &grp_gen[g * 32];
    int mg = __hip_atomic_load(ggen, __ATOMIC_RELAXED, __HIP_MEMORY_SCOPE_AGENT);
    int old = __hip_atomic_fetch_add(gctr, 1, __ATOMIC_ACQ_REL,
                                     __HIP_MEMORY_SCOPE_AGENT);
    if (old == 31) {  // group leader
      int mr = __hip_atomic_load(&root_gen, __ATOMIC_RELAXED,
                                 __HIP_MEMORY_SCOPE_AGENT);
      int o2 = __hip_atomic_fetch_add(&root_ctr, 1, __ATOMIC_ACQ_REL,
                                      __HIP_MEMORY_SCOPE_AGENT);
      if (o2 == 7) {  // last group: reset BEFORE bump
        __hip_atomic_store(&root_ctr, 0, __ATOMIC_RELAXED,
                           __HIP_MEMORY_SCOPE_AGENT);
        __hip_atomic_fetch_add(&root_gen, 1, __ATOMIC_RELEASE,
                               __HIP_MEMORY_SCOPE_AGENT);
      } else {
        spin_gen(&root_gen, mr);  // <=7 pollers on the root line
      }
      // propagate to group: reset ctr, then release-bump group gen
      __hip_atomic_store(gctr, 0, __ATOMIC_RELAXED, __HIP_MEMORY_SCOPE_AGENT);
      __hip_atomic_fetch_add(ggen, 1, __ATOMIC_RELEASE,
                             __HIP_MEMORY_SCOPE_AGENT);
    } else {
      spin_gen(ggen, mg);  // <=31 pollers per group line
    }
  }
  __syncthreads();
  __threadfence();   // acquire: one invalidate before reading peers' data
}

// Flat small barrier for the 32-block c-group (k3 -> k4), RELAXED polls.
__device__ __forceinline__ void barrier_on(int* ctr, int* gen, int nblk) {
  __threadfence();
  __syncthreads();
  if (threadIdx.x == 0) {
    int mygen =
        __hip_atomic_load(gen, __ATOMIC_RELAXED, __HIP_MEMORY_SCOPE_AGENT);
    int old = __hip_atomic_fetch_add(ctr, 1, __ATOMIC_ACQ_REL,
                                     __HIP_MEMORY_SCOPE_AGENT);
    if (old == nblk - 1) {
      __hip_atomic_store(ctr, 0, __ATOMIC_RELAXED, __HIP_MEMORY_SCOPE_AGENT);
      __hip_atomic_fetch_add(gen, 1, __ATOMIC_RELEASE,
                             __HIP_MEMORY_SCOPE_AGENT);
    } else {
      spin_gen(gen, mygen);
    }
  }
  __syncthreads();
  __threadfence();
}

// ONE dispatch: kf (moments) -> tree barrier -> k3 (split-K GEMM) ->
// per-c-group barrier -> k4 (reduce+bias+relu). 256 blocks x 256 threads.
__global__ __launch_bounds__(256, 1) void fused_all(
    const float* __restrict__ visual, const float* __restrict__ text,
    const float* __restrict__ w_vis, const float* __restrict__ w_text,
    const float* __restrict__ bias, const float* __restrict__ W_fv,
    const float* __restrict__ b_fv, const float* __restrict__ W_ft,
    const float* __restrict__ b_ft, float* __restrict__ out,
    float* __restrict__ St, float* __restrict__ part) {
  __shared__ float smem[2 * 32 * 132];  // 33.8 KB, aliased kf/k3
  const int bid = blockIdx.x;
  const int tid = threadIdx.x;

  // ================= Phase kf: moments =================
  {
    const int b = bid >> 1;
    const int h = bid & 1;
    const int lane = tid & 63, wave = tid >> 6;
    float* Rw = smem;        // [4][66]
    float* fin = smem + 264; // [66]

    float mac[66];
#pragma unroll
    for (int r = 0; r < 66; ++r) mac[r] = 0.f;
#pragma unroll
    for (int j = 0; j < 4; ++j) {
      const int t = tid + 256 * j;
      const float w = w_vis[t];
      const float x = text[b * T_ + t];
      float wp[11], xq[11];
      wp[0] = 1.f;
      xq[0] = 1.f;
#pragma unroll
      for (int k = 1; k <= 10; ++k) {
        wp[k] = wp[k - 1] * w;
        xq[k] = xq[k - 1] * x;
      }
#pragma unroll
      for (int i = 0; i <= 10; ++i)
#pragma unroll
        for (int p = 0; p <= i; ++p)
          mac[i * (i + 1) / 2 + p] =
              fmaf(wp[p], xq[i - p], mac[i * (i + 1) / 2 + p]);
    }
#pragma unroll
    for (int m = 1; m <= 32; m <<= 1)
#pragma unroll
      for (int r = 0; r < 66; ++r) mac[r] += __shfl_xor(mac[r], m, 64);
    if (lane == 0) {
#pragma unroll
      for (int r = 0; r < 66; ++r) Rw[wave * 66 + r] = mac[r];
    }
    __syncthreads();
    if (tid < 66)
      fin[tid] = (Rw[0 * 66 + tid] + Rw[1 * 66 + tid]) +
                 (Rw[2 * 66 + tid] + Rw[3 * 66 + tid]);
    __syncthreads();
    float M[66];
#pragma unroll
    for (int r = 0; r < 66; ++r) M[r] = fin[r];

    float nac[55];
#pragma unroll
    for (int r = 0; r < 55; ++r) nac[r] = 0.f;
#pragma unroll
    for (int j = 0; j < 4; ++j) {
      const int v = tid + 256 * j;
      const float al = visual[b * V_ + v];
      const float be = w_text[v];
      const float ga = bias[v];
      float Ah[10], Bh[10];  // a^p/p!, b^q/q!
      Ah[0] = 1.f;
      Bh[0] = 1.f;
      float aw = 1.f, bw = 1.f;
#pragma unroll
      for (int k = 1; k <= 9; ++k) {
        aw *= al;
        Ah[k] = aw * IFC[k];
        bw *= be;
        Bh[k] = bw * IFC[k];
      }
      float dh[10];
#pragma unroll
      for (int i = 0; i < 10; ++i) {
        float a = 0.f;
#pragma unroll
        for (int jj = 9; jj >= i; --jj)
          a = fmaf(a, ga, C9v[jj] * BN[jj][i] * FACT[i]);
        dh[i] = a;
      }
      float T1 = 0.f, T2 = 0.f;
      float hv[55];
#pragma unroll
      for (int i = 0; i <= 9; ++i)
#pragma unroll
        for (int p = 0; p <= i; ++p) {
          const int ix = i * (i + 1) / 2 + p;
          const int ix2 = (i + 1) * (i + 2) / 2 + p;  // (p, q+1)
          hv[ix] = dh[i] * Ah[p] * Bh[i - p];
          T1 = fmaf(hv[ix], M[ix], T1);
          T2 = fmaf(hv[ix], M[ix2], T2);
        }
      const float rd = 1.0f / T1;
      if (h == 0) St[b * KK + T_ + v] = T2 * rd;  // text_score
      const float vod = al * rd;
#pragma unroll
      for (int r = 0; r < 55; ++r) nac[r] = fmaf(hv[r], vod, nac[r]);
    }
#pragma unroll
    for (int m = 1; m <= 32; m <<= 1)
#pragma unroll
      for (int r = 0; r < 55; ++r) nac[r] += __shfl_xor(nac[r], m, 64);
    if (lane == 0) {
#pragma unroll
      for (int r = 0; r < 55; ++r) Rw[wave * 66 + r] = nac[r];
    }
    __syncthreads();
    if (tid < 55)
      fin[tid] = (Rw[0 * 66 + tid] + Rw[1 * 66 + tid]) +
                 (Rw[2 * 66 + tid] + Rw[3 * 66 + tid]);
    __syncthreads();
    float N[55];
#pragma unroll
    for (int r = 0; r < 55; ++r) N[r] = fin[r];

#pragma unroll
    for (int j = 0; j < 2; ++j) {
      const int t = tid + 256 * j + 512 * h;
      const float w = w_vis[t];
      const float x = text[b * T_ + t];
      float wp[10], xq[10];
      wp[0] = 1.f;
      xq[0] = 1.f;
#pragma unroll
      for (int k = 1; k <= 9; ++k) {
        wp[k] = wp[k - 1] * w;
        xq[k] = xq[k - 1] * x;
      }
      float vs = 0.f;
#pragma unroll
      for (int p = 0; p <= 9; ++p) {
        float s = 0.f;
#pragma unroll
        for (int q = 0; q <= 9 - p; ++q)
          s = fmaf(xq[q], N[(p + q) * (p + q + 1) / 2 + p], s);
        vs = fmaf(wp[p], s, vs);
      }
      St[b * KK + t] = vs;  // visual_score
    }
  }

  tree_barrier(bid);  // kf -> k3 (grid-wide, hierarchical)

  // ================= Phase k3: split-K GEMM =================
  const int zz = bid >> 3;
  const int cb = bid & 7;
  {
    float* Ss = smem;             // [32][132] [k][b]
    float* Ws = smem + 32 * 132;  // [32][132] [k][c]
    const int ks = zz * 64;
    const float* __restrict__ W = (ks < T_) ? (W_fv + ks) : (W_ft + (ks - T_));
    const int kq = tid & 3, rr = tid >> 2;
    const int mc = tid & 15, mb = tid >> 4;
    float acc[8][8] = {};
#pragma unroll
    for (int kc0 = 0; kc0 < 64; kc0 += 32) {
      __syncthreads();  // protect smem reuse
#pragma unroll
      for (int jb = 0; jb < 2; ++jb) {
        const int brow = rr + 64 * jb;
#pragma unroll
        for (int jk = 0; jk < 2; ++jk) {
          const int k0 = 4 * kq + 16 * jk;
          float4 g = *(const float4*)&St[brow * KK + ks + kc0 + k0];
          Ss[(k0 + 0) * 132 + brow] = g.x;
          Ss[(k0 + 1) * 132 + brow] = g.y;
          Ss[(k0 + 2) * 132 + brow] = g.z;
          Ss[(k0 + 3) * 132 + brow] = g.w;
        }
      }
#pragma unroll
      for (int jc = 0; jc < 2; ++jc) {
        const int c = rr + 64 * jc;
#pragma unroll
        for (int jk = 0; jk < 2; ++jk) {
          const int k0 = 4 * kq + 16 * jk;
          float4 g = *(const float4*)&W[(cb * 128 + c) * 1024 + kc0 + k0];
          Ws[(k0 + 0) * 132 + c] = g.x;
          Ws[(k0 + 1) * 132 + c] = g.y;
          Ws[(k0 + 2) * 132 + c] = g.z;
          Ws[(k0 + 3) * 132 + c] = g.w;
        }
      }
      __syncthreads();
#pragma unroll 4
      for (int k = 0; k < 32; ++k) {
        const float4 s0 = *(const float4*)&Ss[k * 132 + 4 * mb];
        const float4 s1 = *(const float4*)&Ss[k * 132 + 4 * mb + 64];
        const float4 w0 = *(const float4*)&Ws[k * 132 + 4 * mc];
        const float4 w1 = *(const float4*)&Ws[k * 132 + 4 * mc + 64];
        const float sv[8] = {s0.x, s0.y, s0.z, s0.w, s1.x, s1.y, s1.z, s1.w};
        const float wv[8] = {w0.x, w0.y, w0.z, w0.w, w1.x, w1.y, w1.z, w1.w};
#pragma unroll
        for (int i = 0; i < 8; ++i)
#pragma unroll
          for (int u = 0; u < 8; ++u)
            acc[i][u] = fmaf(sv[i], wv[u], acc[i][u]);
      }
    }
    float* __restrict__ P = part + (size_t)zz * (B_ * C_);
#pragma unroll
    for (int ih = 0; ih < 2; ++ih)
#pragma unroll
      for (int i = 0; i < 4; ++i) {
        const int row = 4 * mb + 64 * ih + i;
#pragma unroll
        for (int jh = 0; jh < 2; ++jh) {
          float4 o = make_float4(acc[ih * 4 + i][jh * 4 + 0],
                                 acc[ih * 4 + i][jh * 4 + 1],
                                 acc[ih * 4 + i][jh * 4 + 2],
                                 acc[ih * 4 + i][jh * 4 + 3]);
          *(float4*)&P[row * C_ + cb * 128 + 4 * mc + 64 * jh] = o;
        }
      }
  }

  // k3 -> k4: only this c-group's 32 z-blocks needed (bid%8==cb -> same XCD).
  barrier_on(&g_gctr[cb * 32], &g_ggen[cb * 32], NZ);

  // ================= Phase k4: reduce + bias + relu =================
  if (tid < 128) {
    const int l = zz * 128 + tid;      // 0..4095 within group
    const int b = l >> 5;              // 128c = 32 float4 per row
    const int c4 = (l & 31) + cb * 32; // float4 col in C
    const float4* P4 = (const float4*)part;
    float4 s = P4[b * (C_ / 4) + c4];
#pragma unroll 8
    for (int z = 1; z < NZ; ++z) {
      float4 p = P4[(size_t)z * (B_ * C_ / 4) + b * (C_ / 4) + c4];
      s.x += p.x;
      s.y += p.y;
      s.z += p.z;
      s.w += p.w;
    }
    float4 bf = ((const float4*)b_fv)[c4];
    float4 bt = ((const float4*)b_ft)[c4];
    float4 o;
    o.x = fmaxf(s.x + bf.x + bt.x, 0.f);
    o.y = fmaxf(s.y + bf.y + bt.y, 0.f);
    o.z = fmaxf(s.z + bf.z + bt.z, 0.f);
    o.w = fmaxf(s.w + bf.w + bt.w, 0.f);
    ((float4*)out)[b * (C_ / 4) + c4] = o;
  }
}

extern "C" void kernel_launch(void* const* d_in, const int* in_sizes, int n_in,
                              void* d_out, int out_size, void* d_ws, size_t ws_size,
                              hipStream_t stream) {
  const float* visual = (const float*)d_in[0];  // [B,V]
  const float* text   = (const float*)d_in[1];  // [B,T]
  const float* w_vis  = (const float*)d_in[2];  // [T]
  const float* w_text = (const float*)d_in[3];  // [V]
  const float* bias   = (const float*)d_in[4];  // [V]
  const float* W_fv   = (const float*)d_in[5];  // [C,T]
  const float* b_fv   = (const float*)d_in[6];  // [C]
  const float* W_ft   = (const float*)d_in[7];  // [C,V]
  const float* b_ft   = (const float*)d_in[8];  // [C]
  float* out = (float*)d_out;                   // [B,C]

  // ws layout (floats): St[B][2048] | part[32][B*C]   (~17 MB)
  float* St = (float*)d_ws;
  float* part = St + (size_t)B_ * KK;

  fused_all<<<dim3(NBLK), dim3(256), 0, stream>>>(
      visual, text, w_vis, w_text, bias, W_fv, b_fv, W_ft, b_ft, out, St, part);
}

// Round 8
// 120.660 us; speedup vs baseline: 1.6221x; 1.6221x over previous
//
#include <hip/hip_runtime.h>

// Problem: B=128, V=1024, T=1024, C=1024
#define B_ 128
#define V_ 1024
#define T_ 1024
#define C_ 1024
#define KK 2048  // T_ + V_
#define NZ 32    // k-slabs in fused k3 phase (K=64 each)
#define NBLK 256

typedef unsigned long long u64;

// Degree-9 Taylor coefficients of f(s) = exp(tanh(s)).
constexpr float C9v[10] = {1.0f,          1.0f,          0.5f,
                           -0.166666667f, -0.291666667f, -0.025f,
                           0.134722222f,  0.054563493f,  -0.051165675f,
                           -0.041377307f};
// Binomial coefficients C(j,p), j<=9
constexpr float BN[10][10] = {
    {1, 0, 0, 0, 0, 0, 0, 0, 0, 0},
    {1, 1, 0, 0, 0, 0, 0, 0, 0, 0},
    {1, 2, 1, 0, 0, 0, 0, 0, 0, 0},
    {1, 3, 3, 1, 0, 0, 0, 0, 0, 0},
    {1, 4, 6, 4, 1, 0, 0, 0, 0, 0},
    {1, 5, 10, 10, 5, 1, 0, 0, 0, 0},
    {1, 6, 15, 20, 15, 6, 1, 0, 0, 0},
    {1, 7, 21, 35, 35, 21, 7, 1, 0, 0},
    {1, 8, 28, 56, 70, 56, 28, 8, 1, 0},
    {1, 9, 36, 84, 126, 126, 84, 36, 9, 1}};
constexpr float FACT[10] = {1.f, 1.f, 2.f, 6.f, 24.f, 120.f,
                            720.f, 5040.f, 40320.f, 362880.f};
constexpr float IFC[10] = {1.f, 1.f, 0.5f, 1.f / 6.f, 1.f / 24.f,
                           1.f / 120.f, 1.f / 720.f, 1.f / 5040.f,
                           1.f / 40320.f, 1.f / 362880.f};

// R7 post-mortem: tree == flat barrier (128.7 vs 128.4) -> contention is NOT
// the cost. Remaining invariant: per-thread __threadfence() (2/barrier) ->
// buffer_wbl2+buffer_inv bulk L2 maintenance, ~1024 ops/barrier serialized
// at each XCD's L2. R8: FENCE-FREE design. All cross-phase data (St, part)
// uses agent-scope RELAXED atomics (sc1 -> LLC-coherent, never stale in
// L1/L2). Release = s_waitcnt vmcnt(0) before arrival (sc1 store ack ==
// visible at LLC). Acquire = nothing. Zero wbl2/inv in the kernel.
__device__ __forceinline__ void st_g32(float* p, float x) {
  __hip_atomic_store((unsigned*)p, __float_as_uint(x), __ATOMIC_RELAXED,
                     __HIP_MEMORY_SCOPE_AGENT);
}
__device__ __forceinline__ void st_g64(float* p, float a, float b) {
  u64 v = (u64)__float_as_uint(a) | ((u64)__float_as_uint(b) << 32);
  __hip_atomic_store((u64*)p, v, __ATOMIC_RELAXED, __HIP_MEMORY_SCOPE_AGENT);
}
__device__ __forceinline__ float2 ld_g64(const float* p) {
  u64 v = __hip_atomic_load((const u64*)p, __ATOMIC_RELAXED,
                            __HIP_MEMORY_SCOPE_AGENT);
  return make_float2(__uint_as_float((unsigned)(v & 0xffffffffu)),
                     __uint_as_float((unsigned)(v >> 32)));
}

__device__ int g_ctr = 0;
__device__ int g_gen = 0;
__device__ int g_gctr[8 * 32];  // k3->k4 per-c-group counters, 128 B apart
__device__ int g_ggen[8 * 32];

// Fence-free generation barrier (proven R5/R6 logic, all-RELAXED atomics).
__device__ __forceinline__ void fence_free_barrier(int* ctr, int* gen, int n) {
  __syncthreads();  // all waves drain (compiler emits vmcnt(0) before s_barrier)
  if (threadIdx.x == 0) {
    // prior sc1 stores are at the LLC once vmcnt==0 (ack from coherence point)
    asm volatile("s_waitcnt vmcnt(0)" ::: "memory");
    int mygen =
        __hip_atomic_load(gen, __ATOMIC_RELAXED, __HIP_MEMORY_SCOPE_AGENT);
    asm volatile("s_waitcnt vmcnt(0)" ::: "memory");  // snapshot before arrival
    int old = __hip_atomic_fetch_add(ctr, 1, __ATOMIC_RELAXED,
                                     __HIP_MEMORY_SCOPE_AGENT);
    if (old == n - 1) {
      __hip_atomic_store(ctr, 0, __ATOMIC_RELAXED, __HIP_MEMORY_SCOPE_AGENT);
      asm volatile("s_waitcnt vmcnt(0)" ::: "memory");  // reset BEFORE bump
      __hip_atomic_fetch_add(gen, 1, __ATOMIC_RELAXED,
                             __HIP_MEMORY_SCOPE_AGENT);
    } else {
      int spins = 0;
      while (__hip_atomic_load(gen, __ATOMIC_RELAXED,
                               __HIP_MEMORY_SCOPE_AGENT) == mygen) {
        __builtin_amdgcn_s_sleep(4);
        if (++spins > (1 << 20)) break;  // failsafe: no infinite hang
      }
    }
  }
  __syncthreads();
}

// ONE dispatch: kf (moments) -> barrier -> k3 (split-K GEMM) -> c-group
// barrier -> k4 (reduce+bias+relu). 256 blocks x 256 threads, 1 block/CU.
__global__ __launch_bounds__(256, 1) void fused_all(
    const float* __restrict__ visual, const float* __restrict__ text,
    const float* __restrict__ w_vis, const float* __restrict__ w_text,
    const float* __restrict__ bias, const float* __restrict__ W_fv,
    const float* __restrict__ b_fv, const float* __restrict__ W_ft,
    const float* __restrict__ b_ft, float* __restrict__ out,
    float* __restrict__ St, float* __restrict__ part) {
  __shared__ float smem[2 * 32 * 132];  // 33.8 KB, aliased kf/k3
  const int bid = blockIdx.x;
  const int tid = threadIdx.x;

  // ================= Phase kf: moments =================
  {
    const int b = bid >> 1;
    const int h = bid & 1;
    const int lane = tid & 63, wave = tid >> 6;
    float* Rw = smem;        // [4][66]
    float* fin = smem + 264; // [66]

    float mac[66];
#pragma unroll
    for (int r = 0; r < 66; ++r) mac[r] = 0.f;
#pragma unroll
    for (int j = 0; j < 4; ++j) {
      const int t = tid + 256 * j;
      const float w = w_vis[t];
      const float x = text[b * T_ + t];
      float wp[11], xq[11];
      wp[0] = 1.f;
      xq[0] = 1.f;
#pragma unroll
      for (int k = 1; k <= 10; ++k) {
        wp[k] = wp[k - 1] * w;
        xq[k] = xq[k - 1] * x;
      }
#pragma unroll
      for (int i = 0; i <= 10; ++i)
#pragma unroll
        for (int p = 0; p <= i; ++p)
          mac[i * (i + 1) / 2 + p] =
              fmaf(wp[p], xq[i - p], mac[i * (i + 1) / 2 + p]);
    }
#pragma unroll
    for (int m = 1; m <= 32; m <<= 1)
#pragma unroll
      for (int r = 0; r < 66; ++r) mac[r] += __shfl_xor(mac[r], m, 64);
    if (lane == 0) {
#pragma unroll
      for (int r = 0; r < 66; ++r) Rw[wave * 66 + r] = mac[r];
    }
    __syncthreads();
    if (tid < 66)
      fin[tid] = (Rw[0 * 66 + tid] + Rw[1 * 66 + tid]) +
                 (Rw[2 * 66 + tid] + Rw[3 * 66 + tid]);
    __syncthreads();
    float M[66];
#pragma unroll
    for (int r = 0; r < 66; ++r) M[r] = fin[r];

    float nac[55];
#pragma unroll
    for (int r = 0; r < 55; ++r) nac[r] = 0.f;
#pragma unroll
    for (int j = 0; j < 4; ++j) {
      const int v = tid + 256 * j;
      const float al = visual[b * V_ + v];
      const float be = w_text[v];
      const float ga = bias[v];
      float Ah[10], Bh[10];  // a^p/p!, b^q/q!
      Ah[0] = 1.f;
      Bh[0] = 1.f;
      float aw = 1.f, bw = 1.f;
#pragma unroll
      for (int k = 1; k <= 9; ++k) {
        aw *= al;
        Ah[k] = aw * IFC[k];
        bw *= be;
        Bh[k] = bw * IFC[k];
      }
      float dh[10];
#pragma unroll
      for (int i = 0; i < 10; ++i) {
        float a = 0.f;
#pragma unroll
        for (int jj = 9; jj >= i; --jj)
          a = fmaf(a, ga, C9v[jj] * BN[jj][i] * FACT[i]);
        dh[i] = a;
      }
      float T1 = 0.f, T2 = 0.f;
      float hv[55];
#pragma unroll
      for (int i = 0; i <= 9; ++i)
#pragma unroll
        for (int p = 0; p <= i; ++p) {
          const int ix = i * (i + 1) / 2 + p;
          const int ix2 = (i + 1) * (i + 2) / 2 + p;  // (p, q+1)
          hv[ix] = dh[i] * Ah[p] * Bh[i - p];
          T1 = fmaf(hv[ix], M[ix], T1);
          T2 = fmaf(hv[ix], M[ix2], T2);
        }
      const float rd = 1.0f / T1;
      if (h == 0) st_g32(&St[b * KK + T_ + v], T2 * rd);  // text_score
      const float vod = al * rd;
#pragma unroll
      for (int r = 0; r < 55; ++r) nac[r] = fmaf(hv[r], vod, nac[r]);
    }
#pragma unroll
    for (int m = 1; m <= 32; m <<= 1)
#pragma unroll
      for (int r = 0; r < 55; ++r) nac[r] += __shfl_xor(nac[r], m, 64);
    if (lane == 0) {
#pragma unroll
      for (int r = 0; r < 55; ++r) Rw[wave * 66 + r] = nac[r];
    }
    __syncthreads();
    if (tid < 55)
      fin[tid] = (Rw[0 * 66 + tid] + Rw[1 * 66 + tid]) +
                 (Rw[2 * 66 + tid] + Rw[3 * 66 + tid]);
    __syncthreads();
    float N[55];
#pragma unroll
    for (int r = 0; r < 55; ++r) N[r] = fin[r];

#pragma unroll
    for (int j = 0; j < 2; ++j) {
      const int t = tid + 256 * j + 512 * h;
      const float w = w_vis[t];
      const float x = text[b * T_ + t];
      float wp[10], xq[10];
      wp[0] = 1.f;
      xq[0] = 1.f;
#pragma unroll
      for (int k = 1; k <= 9; ++k) {
        wp[k] = wp[k - 1] * w;
        xq[k] = xq[k - 1] * x;
      }
      float vs = 0.f;
#pragma unroll
      for (int p = 0; p <= 9; ++p) {
        float s = 0.f;
#pragma unroll
        for (int q = 0; q <= 9 - p; ++q)
          s = fmaf(xq[q], N[(p + q) * (p + q + 1) / 2 + p], s);
        vs = fmaf(wp[p], s, vs);
      }
      st_g32(&St[b * KK + t], vs);  // visual_score
    }
  }

  fence_free_barrier(&g_ctr, &g_gen, NBLK);  // kf -> k3 (grid-wide)

  // ================= Phase k3: split-K GEMM =================
  const int zz = bid >> 3;
  const int cb = bid & 7;
  {
    float* Ss = smem;             // [32][132] [k][b]
    float* Ws = smem + 32 * 132;  // [32][132] [k][c]
    const int ks = zz * 64;
    const float* __restrict__ W = (ks < T_) ? (W_fv + ks) : (W_ft + (ks - T_));
    const int kq = tid & 3, rr = tid >> 2;
    const int mc = tid & 15, mb = tid >> 4;
    float acc[8][8] = {};
#pragma unroll
    for (int kc0 = 0; kc0 < 64; kc0 += 32) {
      __syncthreads();  // protect smem reuse
#pragma unroll
      for (int jb = 0; jb < 2; ++jb) {
        const int brow = rr + 64 * jb;
#pragma unroll
        for (int jk = 0; jk < 2; ++jk) {
          const int k0 = 4 * kq + 16 * jk;
          const float* sp = &St[brow * KK + ks + kc0 + k0];
          float2 ga = ld_g64(sp);      // sc1: LLC-coherent St read
          float2 gb = ld_g64(sp + 2);
          Ss[(k0 + 0) * 132 + brow] = ga.x;
          Ss[(k0 + 1) * 132 + brow] = ga.y;
          Ss[(k0 + 2) * 132 + brow] = gb.x;
          Ss[(k0 + 3) * 132 + brow] = gb.y;
        }
      }
#pragma unroll
      for (int jc = 0; jc < 2; ++jc) {
        const int c = rr + 64 * jc;
#pragma unroll
        for (int jk = 0; jk < 2; ++jk) {
          const int k0 = 4 * kq + 16 * jk;
          float4 g = *(const float4*)&W[(cb * 128 + c) * 1024 + kc0 + k0];
          Ws[(k0 + 0) * 132 + c] = g.x;
          Ws[(k0 + 1) * 132 + c] = g.y;
          Ws[(k0 + 2) * 132 + c] = g.z;
          Ws[(k0 + 3) * 132 + c] = g.w;
        }
      }
      __syncthreads();
#pragma unroll 4
      for (int k = 0; k < 32; ++k) {
        const float4 s0 = *(const float4*)&Ss[k * 132 + 4 * mb];
        const float4 s1 = *(const float4*)&Ss[k * 132 + 4 * mb + 64];
        const float4 w0 = *(const float4*)&Ws[k * 132 + 4 * mc];
        const float4 w1 = *(const float4*)&Ws[k * 132 + 4 * mc + 64];
        const float sv[8] = {s0.x, s0.y, s0.z, s0.w, s1.x, s1.y, s1.z, s1.w};
        const float wv[8] = {w0.x, w0.y, w0.z, w0.w, w1.x, w1.y, w1.z, w1.w};
#pragma unroll
        for (int i = 0; i < 8; ++i)
#pragma unroll
          for (int u = 0; u < 8; ++u)
            acc[i][u] = fmaf(sv[i], wv[u], acc[i][u]);
      }
    }
    float* __restrict__ P = part + (size_t)zz * (B_ * C_);
#pragma unroll
    for (int ih = 0; ih < 2; ++ih)
#pragma unroll
      for (int i = 0; i < 4; ++i) {
        const int row = 4 * mb + 64 * ih + i;
#pragma unroll
        for (int jh = 0; jh < 2; ++jh) {
          float* pp = &P[row * C_ + cb * 128 + 4 * mc + 64 * jh];
          st_g64(pp, acc[ih * 4 + i][jh * 4 + 0], acc[ih * 4 + i][jh * 4 + 1]);
          st_g64(pp + 2, acc[ih * 4 + i][jh * 4 + 2],
                 acc[ih * 4 + i][jh * 4 + 3]);
        }
      }
  }

  // k3 -> k4: only this c-group's 32 z-blocks needed.
  fence_free_barrier(&g_gctr[cb * 32], &g_ggen[cb * 32], NZ);

  // ================= Phase k4: reduce + bias + relu =================
  if (tid < 128) {
    const int l = zz * 128 + tid;      // 0..4095 within group
    const int b = l >> 5;              // 128c = 32 float4 per row
    const int c4 = (l & 31) + cb * 32; // float4 col in C
    const float* p0 = part + b * C_ + 4 * c4;
    float2 sa = ld_g64(p0);
    float2 sb = ld_g64(p0 + 2);
#pragma unroll 8
    for (int z = 1; z < NZ; ++z) {
      const float* pz = p0 + (size_t)z * (B_ * C_);
      float2 pa = ld_g64(pz);
      float2 pb = ld_g64(pz + 2);
      sa.x += pa.x;
      sa.y += pa.y;
      sb.x += pb.x;
      sb.y += pb.y;
    }
    float4 bf = ((const float4*)b_fv)[c4];
    float4 bt = ((const float4*)b_ft)[c4];
    float4 o;
    o.x = fmaxf(sa.x + bf.x + bt.x, 0.f);
    o.y = fmaxf(sa.y + bf.y + bt.y, 0.f);
    o.z = fmaxf(sb.x + bf.z + bt.z, 0.f);
    o.w = fmaxf(sb.y + bf.w + bt.w, 0.f);
    ((float4*)out)[b * (C_ / 4) + c4] = o;
  }
}

extern "C" void kernel_launch(void* const* d_in, const int* in_sizes, int n_in,
                              void* d_out, int out_size, void* d_ws, size_t ws_size,
                              hipStream_t stream) {
  const float* visual = (const float*)d_in[0];  // [B,V]
  const float* text   = (const float*)d_in[1];  // [B,T]
  const float* w_vis  = (const float*)d_in[2];  // [T]
  const float* w_text = (const float*)d_in[3];  // [V]
  const float* bias   = (const float*)d_in[4];  // [V]
  const float* W_fv   = (const float*)d_in[5];  // [C,T]
  const float* b_fv   = (const float*)d_in[6];  // [C]
  const float* W_ft   = (const float*)d_in[7];  // [C,V]
  const float* b_ft   = (const float*)d_in[8];  // [C]
  float* out = (float*)d_out;                   // [B,C]

  // ws layout (floats): St[B][2048] | part[32][B*C]   (~17 MB)
  float* St = (float*)d_ws;
  float* part = St + (size_t)B_ * KK;

  fused_all<<<dim3(NBLK), dim3(256), 0, stream>>>(
      visual, text, w_vis, w_text, bias, W_fv, b_fv, W_ft, b_ft, out, St, part);
}